// Round 5
// baseline (249.967 us; speedup 1.0000x reference)
//
#include <hip/hip_runtime.h>

// FeatureTokenizer: out[b,c,h] = (x[b,c]*W[c,h] + b[c,h])*(1-m[b,c]) + me[h]*m[b,c]
// B=16384, C=128, H=128 -> 1.074 GB f32 output. Write-bandwidth-bound.
//
// R5: remove ALL global loads from the inner loop. Each 32-lane group needs
// x[rc + it*16384] / m[rc + it*16384] for it=0..127. Preload them into 4
// registers per operand (lane t of the group holds trip t+32k), then get the
// per-trip value with __shfl(reg, t, 32)  -> ds_bpermute, which is lgkmcnt,
// NOT vmcnt. The inner loop is then {2 shfl, FMAs, 1 coalesced 16B store}:
// the store stream never waits behind load misses in the in-order vmcnt
// queue, matching the structure of the 6.5 TB/s fill kernel.

typedef float fx4 __attribute__((ext_vector_type(4)));

constexpr int kB = 16384;
constexpr int kC = 128;
constexpr int kH = 128;
constexpr int kH4 = kH / 4;                    // 32 float4 per (b,c) row
constexpr int kTotal4 = kB * kC * kH4;         // 67,108,864
constexpr int kBlock = 256;
constexpr int kGrid = 2048;
constexpr int kStride4 = kGrid * kBlock;       // 524288 float4
constexpr int kIters = kTotal4 / kStride4;     // 128 (exact, no tail)
constexpr int kRcStep = kStride4 / kH4;        // 16384 rows (== 0 mod kC)

__global__ __launch_bounds__(kBlock) void FeatureTokenizer_69664369541889_kernel(
    const float* __restrict__ x,      // (B, C)
    const float* __restrict__ m,      // (B, C)
    const float* __restrict__ W,      // (C, H)
    const float* __restrict__ bias,   // (C, H)
    const float* __restrict__ me,     // (1, H)
    float* __restrict__ out)          // (B, C, H)
{
    const fx4* __restrict__ W4  = reinterpret_cast<const fx4*>(W);
    const fx4* __restrict__ b4  = reinterpret_cast<const fx4*>(bias);
    const fx4* __restrict__ me4 = reinterpret_cast<const fx4*>(me);
    fx4* __restrict__ out4      = reinterpret_cast<fx4*>(out);

    const int idx0 = blockIdx.x * kBlock + threadIdx.x;   // [0, 524288)
    const int h4   = idx0 & (kH4 - 1);
    const int rc   = idx0 >> 5;                           // lanes 0-31: r, 32-63: r+1
    const int cc   = rc & (kC - 1);                       // fixed per thread
    const int l31  = threadIdx.x & 31;                    // lane within 32-group

    // Loop-invariant per-thread tables (L2-resident).
    const fx4 w  = W4[cc * kH4 + h4];
    const fx4 bb = b4[cc * kH4 + h4];
    const fx4 e  = me4[h4];

    // Preload the group's 128 x/m values: lane t of each 32-lane group holds
    // the value for trip t + 32k. All indices static (full unroll).
    float xr[4], mr[4];
#pragma unroll
    for (int k = 0; k < 4; ++k) {
        const int row = rc + (l31 + 32 * k) * kRcStep;
        xr[k] = x[row];
        mr[k] = m[row];
    }

    int oidx = idx0;
#pragma unroll
    for (int k = 0; k < 4; ++k) {      // static xr[k]/mr[k] indexing
#pragma unroll 8
        for (int t = 0; t < 32; ++t) { // trip it = 32k + t
            const float xv = __shfl(xr[k], t, 32);   // ds_bpermute (lgkmcnt)
            const float mv = __shfl(mr[k], t, 32);
            const float om = 1.0f - mv;

            fx4 o;
            o.x = fmaf(fmaf(xv, w.x, bb.x), om, e.x * mv);
            o.y = fmaf(fmaf(xv, w.y, bb.y), om, e.y * mv);
            o.z = fmaf(fmaf(xv, w.z, bb.z), om, e.z * mv);
            o.w = fmaf(fmaf(xv, w.w, bb.w), om, e.w * mv);

            out4[oidx] = o;            // the ONLY vmcnt op in the loop
            oidx += kStride4;
        }
    }
}

extern "C" void kernel_launch(void* const* d_in, const int* in_sizes, int n_in,
                              void* d_out, int out_size, void* d_ws, size_t ws_size,
                              hipStream_t stream) {
    const float* x    = (const float*)d_in[0];  // x_numerical (B, C)
    const float* m    = (const float*)d_in[1];  // mask (B, C)
    const float* W    = (const float*)d_in[2];  // W (C, H)
    const float* bias = (const float*)d_in[3];  // b (C, H)
    const float* me   = (const float*)d_in[4];  // mask_embedding (1, H)
    float* out        = (float*)d_out;

    FeatureTokenizer_69664369541889_kernel<<<kGrid, kBlock, 0, stream>>>(x, m, W, bias, me, out);
}

// Round 6
// 249.650 us; speedup vs baseline: 1.0013x; 1.0013x over previous
//
#include <hip/hip_runtime.h>

// FeatureTokenizer: out[b,c,h] = (x[b,c]*W[c,h] + b[c,h])*(1-m[b,c]) + me[h]*m[b,c]
// B=16384, C=128, H=128 -> 1.074 GB f32 output. Write-bandwidth-bound.
//
// R6: SMALL GRID. The harness's own fillBufferAligned sustains 6.5 TB/s at
// ~10.9% occupancy (~3.5 waves/CU, ~900 waves). Our previous 8192-wave
// launches all plateaued at 4.6 TB/s regardless of inner-loop structure
// (loads / NT / shfl) -> the variable left is the number of concurrent
// write streams. grid=256 (1 block/CU, 4 waves/CU, 1024 waves) mimics the
// fill's concurrency. Structure otherwise identical to R4: hoisted
// loop-invariant W/b/me, 2 broadcast loads + FMAs + one 16B store, unroll 8.

typedef float fx4 __attribute__((ext_vector_type(4)));

constexpr int kB = 16384;
constexpr int kC = 128;
constexpr int kH = 128;
constexpr int kH4 = kH / 4;                    // 32 float4 per (b,c) row
constexpr int kTotal4 = kB * kC * kH4;         // 67,108,864
constexpr int kBlock = 256;
constexpr int kGrid = 256;                     // 1 block/CU, 4 waves/CU
constexpr int kStride4 = kGrid * kBlock;       // 65536 float4
constexpr int kIters = kTotal4 / kStride4;     // 1024 (exact, no tail)
constexpr int kRcStep = kStride4 / kH4;        // 2048 rows (== 0 mod kC)

__global__ __launch_bounds__(kBlock) void FeatureTokenizer_69664369541889_kernel(
    const float* __restrict__ x,      // (B, C)
    const float* __restrict__ m,      // (B, C)
    const float* __restrict__ W,      // (C, H)
    const float* __restrict__ bias,   // (C, H)
    const float* __restrict__ me,     // (1, H)
    float* __restrict__ out)          // (B, C, H)
{
    const fx4* __restrict__ W4  = reinterpret_cast<const fx4*>(W);
    const fx4* __restrict__ b4  = reinterpret_cast<const fx4*>(bias);
    const fx4* __restrict__ me4 = reinterpret_cast<const fx4*>(me);
    fx4* __restrict__ out4      = reinterpret_cast<fx4*>(out);

    const int idx0 = blockIdx.x * kBlock + threadIdx.x;   // [0, 65536)
    const int h4   = idx0 & (kH4 - 1);
    int rc         = idx0 >> 5;                           // [0, 2048)
    const int cc   = rc & (kC - 1);                       // fixed per thread

    // Loop-invariant per-thread tables (L2-resident).
    const fx4 w  = W4[cc * kH4 + h4];
    const fx4 bb = b4[cc * kH4 + h4];
    const fx4 e  = me4[h4];

    int oidx = idx0;
#pragma unroll 8
    for (int it = 0; it < kIters; ++it) {
        const float xv = x[rc];       // 32 lanes broadcast same dword
        const float mv = m[rc];
        const float om = 1.0f - mv;

        fx4 o;
        o.x = fmaf(fmaf(xv, w.x, bb.x), om, e.x * mv);
        o.y = fmaf(fmaf(xv, w.y, bb.y), om, e.y * mv);
        o.z = fmaf(fmaf(xv, w.z, bb.z), om, e.z * mv);
        o.w = fmaf(fmaf(xv, w.w, bb.w), om, e.w * mv);

        out4[oidx] = o;
        rc   += kRcStep;
        oidx += kStride4;
    }
}

extern "C" void kernel_launch(void* const* d_in, const int* in_sizes, int n_in,
                              void* d_out, int out_size, void* d_ws, size_t ws_size,
                              hipStream_t stream) {
    const float* x    = (const float*)d_in[0];  // x_numerical (B, C)
    const float* m    = (const float*)d_in[1];  // mask (B, C)
    const float* W    = (const float*)d_in[2];  // W (C, H)
    const float* bias = (const float*)d_in[3];  // b (C, H)
    const float* me   = (const float*)d_in[4];  // mask_embedding (1, H)
    float* out        = (float*)d_out;

    FeatureTokenizer_69664369541889_kernel<<<kGrid, kBlock, 0, stream>>>(x, m, W, bias, me, out);
}